// Round 5
// baseline (372.194 us; speedup 1.0000x reference)
//
#include <hip/hip_runtime.h>
#include <cstdint>
#include <cstddef>

#define N_NODES 4096
#define EMB 10
#define BATCH_SZ 64
#define CI 64
#define CO 64
#define LKP 136   // node_gemm pad

// diffuse GEMM geometry
#define BM 256
#define BN 128
#define SLOT_U16 24576   // 48 KB slot in u16
#define BOFF_U16 16384   // B-region offset within slot (32 KB)

typedef unsigned short u16;
typedef __bf16 bf16x8 __attribute__((ext_vector_type(8)));
typedef float f32x4 __attribute__((ext_vector_type(4)));

__device__ __forceinline__ u16 f2bf(float f) {
  union { float f; uint32_t u; } v; v.f = f;
  const uint32_t r = v.u + 0x7fffu + ((v.u >> 16) & 1u);  // RNE (finite inputs)
  return (u16)(r >> 16);
}

__device__ __forceinline__ void gload16(const void* g, void* l) {
  __builtin_amdgcn_global_load_lds(
      (__attribute__((address_space(1))) void*)(g),
      (__attribute__((address_space(3))) void*)(l), 16, 0, 0);
}

// ---------------------------------------------------------------------------
// Kernel A: S[n,:] = softmax(relu(E[n,:] @ E^T)) -> bf16.  4 rows per block.
// ---------------------------------------------------------------------------
__global__ __launch_bounds__(256) void support_softmax(
    const float* __restrict__ E, u16* __restrict__ Sb) {
  __shared__ float sim[4][N_NODES];   // 64 KB
  __shared__ float EnS[4][EMB];
  __shared__ float red[4][4];
  const int n0 = blockIdx.x * 4;
  const int t = threadIdx.x;
  const int wid = t >> 6;
  if (t < 4 * EMB) EnS[t / EMB][t % EMB] = E[n0 * EMB + t];
  __syncthreads();
  float en[4][EMB];
#pragma unroll
  for (int r = 0; r < 4; ++r)
#pragma unroll
    for (int d = 0; d < EMB; ++d) en[r][d] = EnS[r][d];

  float rmax[4] = {-1e30f, -1e30f, -1e30f, -1e30f};
  for (int p = 0; p < 16; ++p) {
    const int m = p * 256 + t;
    const float2* e2 = reinterpret_cast<const float2*>(E + m * EMB);
    float em[EMB];
    const float2 v0 = e2[0], v1 = e2[1], v2 = e2[2], v3 = e2[3], v4 = e2[4];
    em[0] = v0.x; em[1] = v0.y; em[2] = v1.x; em[3] = v1.y; em[4] = v2.x;
    em[5] = v2.y; em[6] = v3.x; em[7] = v3.y; em[8] = v4.x; em[9] = v4.y;
#pragma unroll
    for (int r = 0; r < 4; ++r) {
      float acc = 0.f;
#pragma unroll
      for (int d = 0; d < EMB; ++d) acc += en[r][d] * em[d];
      acc = fmaxf(acc, 0.f);
      sim[r][m] = acc;
      rmax[r] = fmaxf(rmax[r], acc);
    }
  }
#pragma unroll
  for (int r = 0; r < 4; ++r) {
#pragma unroll
    for (int s = 32; s; s >>= 1) rmax[r] = fmaxf(rmax[r], __shfl_xor(rmax[r], s));
  }
  if ((t & 63) == 0) {
#pragma unroll
    for (int r = 0; r < 4; ++r) red[r][wid] = rmax[r];
  }
  __syncthreads();
  float gmax[4];
#pragma unroll
  for (int r = 0; r < 4; ++r)
    gmax[r] = fmaxf(fmaxf(red[r][0], red[r][1]), fmaxf(red[r][2], red[r][3]));
  __syncthreads();

  float rsum[4] = {0.f, 0.f, 0.f, 0.f};
  for (int p = 0; p < 16; ++p) {
    const int m = p * 256 + t;
#pragma unroll
    for (int r = 0; r < 4; ++r) {
      const float e = __expf(sim[r][m] - gmax[r]);
      sim[r][m] = e;
      rsum[r] += e;
    }
  }
#pragma unroll
  for (int r = 0; r < 4; ++r) {
#pragma unroll
    for (int s = 32; s; s >>= 1) rsum[r] += __shfl_xor(rsum[r], s);
  }
  if ((t & 63) == 0) {
#pragma unroll
    for (int r = 0; r < 4; ++r) red[r][wid] = rsum[r];
  }
  __syncthreads();
  float inv[4];
#pragma unroll
  for (int r = 0; r < 4; ++r)
    inv[r] = 1.0f / (red[r][0] + red[r][1] + red[r][2] + red[r][3]);

  for (int p = 0; p < 16; ++p) {
    const int m = p * 256 + t;
#pragma unroll
    for (int r = 0; r < 4; ++r)
      Sb[(size_t)(n0 + r) * N_NODES + m] = f2bf(sim[r][m] * inv[r]);
  }
}

// ---------------------------------------------------------------------------
// Kernel A2: Xt[j][m] = bf16(x[b][m][c]),  j = b*64 + c
// ---------------------------------------------------------------------------
__global__ __launch_bounds__(256) void convert_x(
    const float* __restrict__ x, u16* __restrict__ Xt) {
  __shared__ float sm[64][65];
  const int b = blockIdx.x, mt = blockIdx.y;
  const int t = threadIdx.x;
  const int c = t & 63, q = t >> 6;
  const float* xp = x + ((size_t)b * N_NODES + mt * 64) * CI;
#pragma unroll
  for (int p = 0; p < 16; ++p) {
    const int r = q + p * 4;
    sm[r][c] = xp[(size_t)r * CI + c];
  }
  __syncthreads();
  u16* op = Xt + (size_t)(b * 64) * N_NODES + mt * 64;
#pragma unroll
  for (int p = 0; p < 16; ++p) {
    const int cc = q + p * 4;
    op[(size_t)cc * N_NODES + c] = f2bf(sm[c][cc]);
  }
}

// ---------------------------------------------------------------------------
// Kernel B: Zb = S @ Xt^T, bf16 MFMA, 3-slot-ring deep pipeline (R4-proven).
// NEW: per-XCD 8x8 tile regions (2x4 region grid) to cut L2 fill traffic.
// ---------------------------------------------------------------------------
__global__ __launch_bounds__(512) void diffuse_gemm_pipe(
    const u16* __restrict__ S, const u16* __restrict__ Xt,
    u16* __restrict__ Zb) {
  __shared__ __align__(16) u16 lds[3 * SLOT_U16];   // 144 KB
  const int tid = threadIdx.x;
  const int lane = tid & 63;
  const int w = tid >> 6;                 // wave 0..7
  // XCD-region swizzle: XCD = bid&7 owns an 8(by) x 8(bx) region.
  // Inner order: by-pairs innermost (B panel reuse), then bx (A panels hot).
  const int bid = blockIdx.x;
  const int xcd = bid & 7;
  const int inner = bid >> 3;             // 0..63
  const int by = (xcd >> 2) * 8 + (inner >> 4) * 2 + (inner & 1);
  const int bx = (xcd & 3) * 8 + ((inner >> 1) & 7);
  const int n0 = by * BM;
  const int j0 = bx * BN;

  // staging maps: 48 chunks of 8 rows x 128 B; wave w owns chunks w*6+i.
  const int lrow8 = lane >> 3;
  const int scol = 8 * ((lane & 7) ^ lrow8);      // pre-swizzled global col
  const u16* gsrc[6];
  const u16* lbase[6];
#pragma unroll
  for (int i = 0; i < 6; ++i) {
    const int chunk = w * 6 + i;
    if (chunk < 32) {   // A chunk
      const int row = chunk * 8 + lrow8;          // 0..255
      gsrc[i] = S + (size_t)(n0 + row) * N_NODES + scol;
      lbase[i] = &lds[chunk * 512];
    } else {            // B chunk
      const int row = (chunk - 32) * 8 + lrow8;   // 0..127
      gsrc[i] = Xt + (size_t)(j0 + row) * N_NODES + scol;
      lbase[i] = &lds[BOFF_U16 + (chunk - 32) * 512];
    }
  }

  const int wm = w >> 1, wn = w & 1;
  const int fr = lane & 15;
  const int khalf = lane >> 4;
  const int swz16 = (fr & 7) << 3;

  f32x4 acc[4][4];
#pragma unroll
  for (int i = 0; i < 4; ++i)
#pragma unroll
    for (int j = 0; j < 4; ++j) acc[i][j] = (f32x4)0.f;

#define STAGE(tt)                                                         \
  {                                                                       \
    const int _s = (tt) % 3;                                              \
    _Pragma("unroll")                                                     \
    for (int i = 0; i < 6; ++i)                                           \
      gload16(gsrc[i] + (size_t)(tt) * 64,                                \
              (void*)(lbase[i] + _s * SLOT_U16));                         \
  }

#define COMPUTE(ss)                                                       \
  {                                                                       \
    const u16* sa = &lds[(ss) * SLOT_U16];                                \
    const u16* sb = sa + BOFF_U16;                                        \
    _Pragma("unroll")                                                     \
    for (int ks = 0; ks < 2; ++ks) {                                      \
      const int c16 = (ks * 32 + khalf * 8) ^ swz16;                      \
      bf16x8 a[4], b[4];                                                  \
      _Pragma("unroll")                                                   \
      for (int fm = 0; fm < 4; ++fm)                                      \
        a[fm] = *reinterpret_cast<const bf16x8*>(                         \
            &sa[(wm * 64 + fm * 16 + fr) * 64 + c16]);                    \
      _Pragma("unroll")                                                   \
      for (int fn = 0; fn < 4; ++fn)                                      \
        b[fn] = *reinterpret_cast<const bf16x8*>(                         \
            &sb[(wn * 64 + fn * 16 + fr) * 64 + c16]);                    \
      __builtin_amdgcn_s_setprio(1);                                      \
      _Pragma("unroll")                                                   \
      for (int fm = 0; fm < 4; ++fm)                                      \
        _Pragma("unroll")                                                 \
        for (int fn = 0; fn < 4; ++fn)                                    \
          acc[fm][fn] = __builtin_amdgcn_mfma_f32_16x16x32_bf16(          \
              a[fm], b[fn], acc[fm][fn], 0, 0, 0);                        \
      __builtin_amdgcn_s_setprio(0);                                      \
    }                                                                     \
  }

  STAGE(0);
  STAGE(1);

  int s = 0;
  for (int t = 0; t < 62; ++t) {
    asm volatile("s_waitcnt vmcnt(6)" ::: "memory");   // tile t landed
    __builtin_amdgcn_s_barrier();
    __builtin_amdgcn_sched_barrier(0);
    STAGE(t + 2);
    COMPUTE(s);
    s = (s == 2) ? 0 : s + 1;
  }
  asm volatile("s_waitcnt vmcnt(6)" ::: "memory");
  __builtin_amdgcn_s_barrier();
  __builtin_amdgcn_sched_barrier(0);
  COMPUTE(s);
  s = (s == 2) ? 0 : s + 1;
  asm volatile("s_waitcnt vmcnt(0)" ::: "memory");
  __builtin_amdgcn_s_barrier();
  __builtin_amdgcn_sched_barrier(0);
  COMPUTE(s);

  const int crow = (lane >> 4) * 4;
  const int ccol = lane & 15;
#pragma unroll
  for (int fm = 0; fm < 4; ++fm) {
    const int nrow = n0 + wm * 64 + fm * 16 + crow;
#pragma unroll
    for (int fn = 0; fn < 4; ++fn) {
      const int jcol = j0 + wn * 64 + fn * 16 + ccol;
#pragma unroll
      for (int r = 0; r < 4; ++r)
        Zb[(size_t)(nrow + r) * N_NODES + jcol] = f2bf(acc[fm][fn][r]);
    }
  }
#undef STAGE
#undef COMPUTE
}

// ---------------------------------------------------------------------------
// Kernel W: Wall[n][ki][o] = bf16( sum_d E[n,d] * wp[d][ki][o] ),  ki=k*64+i.
// 64 nodes/block; wp slice held in registers (float4 over o), E in LDS,
// broadcast reads over the 64-node loop.  Aliases dead Sb+Xt workspace.
// ---------------------------------------------------------------------------
__global__ __launch_bounds__(256) void wgen(
    const float* __restrict__ E, const float* __restrict__ wp,
    u16* __restrict__ Wall) {
  __shared__ float en_s[64][EMB];
  const int n0 = blockIdx.x * 64;
  const int t = threadIdx.x;
#pragma unroll
  for (int p = 0; p < 3; ++p) {
    const int idx = p * 256 + t;
    if (idx < 64 * EMB) en_s[idx / EMB][idx % EMB] = E[n0 * EMB + idx];
  }
  __syncthreads();

  const float4* wp4 = reinterpret_cast<const float4*>(wp);
#pragma unroll
  for (int it = 0; it < 8; ++it) {
    const int slot = it * 256 + t;      // 0..2047 = ki*16 + o4
    const int ki = slot >> 4, o4 = slot & 15;
    float4 wv[EMB];
#pragma unroll
    for (int d = 0; d < EMB; ++d) wv[d] = wp4[d * 2048 + slot];
#pragma unroll 8
    for (int n = 0; n < 64; ++n) {
      float ax = 0.f, ay = 0.f, az = 0.f, aw = 0.f;
#pragma unroll
      for (int d = 0; d < EMB; ++d) {
        const float e = en_s[n][d];
        ax += e * wv[d].x; ay += e * wv[d].y;
        az += e * wv[d].z; aw += e * wv[d].w;
      }
      ushort4 uv;
      uv.x = f2bf(ax); uv.y = f2bf(ay); uv.z = f2bf(az); uv.w = f2bf(aw);
      *reinterpret_cast<ushort4*>(
          &Wall[((size_t)(n0 + n) * 128 + ki) * 64 + o4 * 4]) = uv;
    }
  }
}

// ---------------------------------------------------------------------------
// Kernel C: per-node MFMA GEMM.  W loaded from Wall (no per-block regen).
// ---------------------------------------------------------------------------
__global__ __launch_bounds__(256) void node_gemm_mfma(
    const float* __restrict__ x, const u16* __restrict__ Zb,
    const u16* __restrict__ Wall, const float* __restrict__ E,
    const float* __restrict__ bp, float* __restrict__ out) {
  __shared__ __align__(16) u16 Wt[2][64][LKP];    // [node][o][ki]
  __shared__ __align__(16) u16 Axz[2][64][LKP];   // [node][b][r]
  __shared__ float biasS[2][64];
  __shared__ float EnS[2][EMB];
  const int n0 = blockIdx.x * 2;
  const int t = threadIdx.x;
  const int lane = t & 63;
  const int w = t >> 6;
  if (t < 2 * EMB) EnS[t / EMB][t % EMB] = E[n0 * EMB + t];
  __syncthreads();

  if (t < 128) {
    const int nn = t >> 6, o = t & 63;
    float b = 0.f;
#pragma unroll
    for (int d = 0; d < EMB; ++d) b += EnS[nn][d] * bp[d * CO + o];
    biasS[nn][o] = b;
  }

  // load Wall[n][ki][o] -> Wt[nn][o][ki] (transposed, padded)
#pragma unroll
  for (int nn = 0; nn < 2; ++nn) {
    const u16* wsrc = Wall + (size_t)(n0 + nn) * 8192;
#pragma unroll
    for (int p = 0; p < 4; ++p) {
      const int slot = p * 256 + t;          // ki*8 + o8
      const int ki = slot >> 3, o8 = slot & 7;
      const ushort4 v0 = *reinterpret_cast<const ushort4*>(&wsrc[ki * 64 + o8 * 8]);
      const ushort4 v1 = *reinterpret_cast<const ushort4*>(&wsrc[ki * 64 + o8 * 8 + 4]);
      Wt[nn][o8 * 8 + 0][ki] = v0.x; Wt[nn][o8 * 8 + 1][ki] = v0.y;
      Wt[nn][o8 * 8 + 2][ki] = v0.z; Wt[nn][o8 * 8 + 3][ki] = v0.w;
      Wt[nn][o8 * 8 + 4][ki] = v1.x; Wt[nn][o8 * 8 + 5][ki] = v1.y;
      Wt[nn][o8 * 8 + 6][ki] = v1.z; Wt[nn][o8 * 8 + 7][ki] = v1.w;
    }
  }

  // stage x (r = 0..63) and Z (r = 64..127), bf16
#pragma unroll
  for (int nn = 0; nn < 2; ++nn) {
    const int ng = n0 + nn;
#pragma unroll
    for (int pb = 0; pb < 4; ++pb) {
      const int b = pb * 16 + (t >> 4);
      const int i0 = (t & 15) * 4;
      const float4 xv = *reinterpret_cast<const float4*>(
          &x[(size_t)b * (N_NODES * CI) + (size_t)ng * CI + i0]);
      ushort4 uv;
      uv.x = f2bf(xv.x); uv.y = f2bf(xv.y); uv.z = f2bf(xv.z); uv.w = f2bf(xv.w);
      *reinterpret_cast<ushort4*>(&Axz[nn][b][i0]) = uv;
    }
#pragma unroll
    for (int pz = 0; pz < 4; ++pz) {
      const int t4 = pz * 256 + t;
      const int b = t4 >> 4, c0 = (t4 & 15) * 4;
      const ushort4 zv = *reinterpret_cast<const ushort4*>(
          &Zb[(size_t)ng * N_NODES + t4 * 4]);
      *reinterpret_cast<ushort4*>(&Axz[nn][b][64 + c0]) = zv;
    }
  }
  __syncthreads();

  const int nn = w >> 1, bh = w & 1;
  const int fr = lane & 15, fk = (lane >> 4) * 8;
  f32x4 acc[2][4];
#pragma unroll
  for (int m = 0; m < 2; ++m)
#pragma unroll
    for (int n = 0; n < 4; ++n) acc[m][n] = (f32x4)0.f;

#pragma unroll
  for (int kk = 0; kk < 4; ++kk) {
    bf16x8 a[2], b[4];
#pragma unroll
    for (int m = 0; m < 2; ++m)
      a[m] = *reinterpret_cast<const bf16x8*>(
          &Axz[nn][bh * 32 + m * 16 + fr][kk * 32 + fk]);
#pragma unroll
    for (int n = 0; n < 4; ++n)
      b[n] = *reinterpret_cast<const bf16x8*>(
          &Wt[nn][n * 16 + fr][kk * 32 + fk]);
#pragma unroll
    for (int m = 0; m < 2; ++m)
#pragma unroll
      for (int n = 0; n < 4; ++n)
        acc[m][n] = __builtin_amdgcn_mfma_f32_16x16x32_bf16(
            a[m], b[n], acc[m][n], 0, 0, 0);
  }

  const int crow = (lane >> 4) * 4;
  const int ccol = lane & 15;
  const int ng = n0 + nn;
#pragma unroll
  for (int m = 0; m < 2; ++m) {
#pragma unroll
    for (int n = 0; n < 4; ++n) {
      const int o = n * 16 + ccol;
      const float bv = biasS[nn][o];
#pragma unroll
      for (int r = 0; r < 4; ++r) {
        const int b = bh * 32 + m * 16 + crow + r;
        out[(size_t)b * (N_NODES * CI) + (size_t)ng * CI + o] =
            acc[m][n][r] + bv;
      }
    }
  }
}

// ---------------------------------------------------------------------------
extern "C" void kernel_launch(void* const* d_in, const int* in_sizes, int n_in,
                              void* d_out, int out_size, void* d_ws, size_t ws_size,
                              hipStream_t stream) {
  const float* x  = (const float*)d_in[0];   // [64, 4096, 64]
  const float* E  = (const float*)d_in[1];   // [4096, 10]
  const float* wp = (const float*)d_in[2];   // [10, 2, 64, 64]
  const float* bp = (const float*)d_in[3];   // [10, 64]
  float* out = (float*)d_out;                // [64, 4096, 64]
  const size_t MAT = (size_t)N_NODES * N_NODES;
  u16* Sb = (u16*)d_ws;                      // bf16 S    (33.5 MB)
  u16* Xt = Sb + MAT;                        // bf16 X^T  (33.5 MB)
  u16* Zb = Xt + MAT;                        // bf16 Z    (33.5 MB)
  u16* Wall = (u16*)d_ws;                    // 67 MB, aliases Sb+Xt (dead
                                             // after diffuse_gemm_pipe)

  support_softmax<<<N_NODES / 4, 256, 0, stream>>>(E, Sb);
  convert_x<<<dim3(BATCH_SZ, N_NODES / 64), 256, 0, stream>>>(x, Xt);
  diffuse_gemm_pipe<<<512, 512, 0, stream>>>(Sb, Xt, Zb);
  wgen<<<N_NODES / 64, 256, 0, stream>>>(E, wp, Wall);
  node_gemm_mfma<<<N_NODES / 2, 256, 0, stream>>>(x, Zb, Wall, E, bp, out);
}

// Round 6
// 308.097 us; speedup vs baseline: 1.2080x; 1.2080x over previous
//
#include <hip/hip_runtime.h>
#include <cstdint>
#include <cstddef>

#define N_NODES 4096
#define EMB 10
#define BATCH_SZ 64
#define CI 64
#define CO 64
#define LKP 136   // node_gemm pad

// diffuse GEMM geometry
#define BM 256
#define BN 128
#define SLOT_U16 24576   // 48 KB slot in u16
#define BOFF_U16 16384   // B-region offset within slot (32 KB)

typedef unsigned short u16;
typedef __bf16 bf16x8 __attribute__((ext_vector_type(8)));
typedef float f32x4 __attribute__((ext_vector_type(4)));

__device__ __forceinline__ u16 f2bf(float f) {
  union { float f; uint32_t u; } v; v.f = f;
  const uint32_t r = v.u + 0x7fffu + ((v.u >> 16) & 1u);  // RNE (finite inputs)
  return (u16)(r >> 16);
}

__device__ __forceinline__ void gload16(const void* g, void* l) {
  __builtin_amdgcn_global_load_lds(
      (__attribute__((address_space(1))) void*)(g),
      (__attribute__((address_space(3))) void*)(l), 16, 0, 0);
}

// ---------------------------------------------------------------------------
// Kernel F: fused front end.
//  blocks [0, 1024):    S[n,:] = softmax(relu(E@E^T)) -> bf16, 4 rows/block
//  blocks [1024, 5120): Xt[b*64+c][m] = bf16(x[b][m][c])  (64x64 tile each)
// ---------------------------------------------------------------------------
__global__ __launch_bounds__(256) void front_fused(
    const float* __restrict__ E, const float* __restrict__ x,
    u16* __restrict__ Sb, u16* __restrict__ Xt) {
  __shared__ float sbuf[4][N_NODES];   // 64 KB (sim rows / transpose tile)
  __shared__ float EnS[4][EMB];
  __shared__ float red[4][4];
  const int t = threadIdx.x;

  if (blockIdx.x < 1024) {
    // ---- softmax part ----
    const int n0 = blockIdx.x * 4;
    const int wid = t >> 6;
    if (t < 4 * EMB) EnS[t / EMB][t % EMB] = E[n0 * EMB + t];
    __syncthreads();
    float en[4][EMB];
#pragma unroll
    for (int r = 0; r < 4; ++r)
#pragma unroll
      for (int d = 0; d < EMB; ++d) en[r][d] = EnS[r][d];

    float rmax[4] = {-1e30f, -1e30f, -1e30f, -1e30f};
    for (int p = 0; p < 16; ++p) {
      const int m = p * 256 + t;
      const float2* e2 = reinterpret_cast<const float2*>(E + m * EMB);
      float em[EMB];
      const float2 v0 = e2[0], v1 = e2[1], v2 = e2[2], v3 = e2[3], v4 = e2[4];
      em[0] = v0.x; em[1] = v0.y; em[2] = v1.x; em[3] = v1.y; em[4] = v2.x;
      em[5] = v2.y; em[6] = v3.x; em[7] = v3.y; em[8] = v4.x; em[9] = v4.y;
#pragma unroll
      for (int r = 0; r < 4; ++r) {
        float acc = 0.f;
#pragma unroll
        for (int d = 0; d < EMB; ++d) acc += en[r][d] * em[d];
        acc = fmaxf(acc, 0.f);
        sbuf[r][m] = acc;
        rmax[r] = fmaxf(rmax[r], acc);
      }
    }
#pragma unroll
    for (int r = 0; r < 4; ++r) {
#pragma unroll
      for (int s = 32; s; s >>= 1) rmax[r] = fmaxf(rmax[r], __shfl_xor(rmax[r], s));
    }
    if ((t & 63) == 0) {
#pragma unroll
      for (int r = 0; r < 4; ++r) red[r][wid] = rmax[r];
    }
    __syncthreads();
    float gmax[4];
#pragma unroll
    for (int r = 0; r < 4; ++r)
      gmax[r] = fmaxf(fmaxf(red[r][0], red[r][1]), fmaxf(red[r][2], red[r][3]));
    __syncthreads();

    float rsum[4] = {0.f, 0.f, 0.f, 0.f};
    for (int p = 0; p < 16; ++p) {
      const int m = p * 256 + t;
#pragma unroll
      for (int r = 0; r < 4; ++r) {
        const float e = __expf(sbuf[r][m] - gmax[r]);
        sbuf[r][m] = e;
        rsum[r] += e;
      }
    }
#pragma unroll
    for (int r = 0; r < 4; ++r) {
#pragma unroll
      for (int s = 32; s; s >>= 1) rsum[r] += __shfl_xor(rsum[r], s);
    }
    if ((t & 63) == 0) {
#pragma unroll
      for (int r = 0; r < 4; ++r) red[r][wid] = rsum[r];
    }
    __syncthreads();
    float inv[4];
#pragma unroll
    for (int r = 0; r < 4; ++r)
      inv[r] = 1.0f / (red[r][0] + red[r][1] + red[r][2] + red[r][3]);

    for (int p = 0; p < 16; ++p) {
      const int m = p * 256 + t;
#pragma unroll
      for (int r = 0; r < 4; ++r)
        Sb[(size_t)(n0 + r) * N_NODES + m] = f2bf(sbuf[r][m] * inv[r]);
    }
  } else {
    // ---- x transpose/convert part ----
    const int idx = blockIdx.x - 1024;
    const int b = idx & 63, mt = idx >> 6;
    float (*sm)[65] = reinterpret_cast<float (*)[65]>(&sbuf[0][0]);
    const int c = t & 63, q = t >> 6;
    const float* xp = x + ((size_t)b * N_NODES + mt * 64) * CI;
#pragma unroll
    for (int p = 0; p < 16; ++p) {
      const int r = q + p * 4;
      sm[r][c] = xp[(size_t)r * CI + c];
    }
    __syncthreads();
    u16* op = Xt + (size_t)(b * 64) * N_NODES + mt * 64;
#pragma unroll
    for (int p = 0; p < 16; ++p) {
      const int cc = q + p * 4;
      op[(size_t)cc * N_NODES + c] = f2bf(sm[c][cc]);
    }
  }
}

// ---------------------------------------------------------------------------
// Kernel B: Zb = S @ Xt^T, bf16 MFMA, 3-slot ring + m201-style 2-phase
// barrier-aligned K-tile schedule.  BM=256, BN=128, BK=64, 8 waves (4m x 2n),
// per-wave 64x64 out.  Data sync: vmcnt(6) + B0 barrier per tile (ring
// invariant, proven R4/R5); intra-tile barriers are pure phase alignment.
// ---------------------------------------------------------------------------
__global__ __launch_bounds__(512) void diffuse_gemm_pipe(
    const u16* __restrict__ S, const u16* __restrict__ Xt,
    u16* __restrict__ Zb) {
  __shared__ __align__(16) u16 lds[3 * SLOT_U16];   // 144 KB
  const int tid = threadIdx.x;
  const int lane = tid & 63;
  const int w = tid >> 6;                 // wave 0..7
  // XCD-region swizzle: XCD = bid&7 owns an 8(by) x 8(bx) region.
  const int bid = blockIdx.x;
  const int xcd = bid & 7;
  const int inner = bid >> 3;             // 0..63
  const int by = (xcd >> 2) * 8 + (inner >> 4) * 2 + (inner & 1);
  const int bx = (xcd & 3) * 8 + ((inner >> 1) & 7);
  const int n0 = by * BM;
  const int j0 = bx * BN;

  // staging maps: 48 chunks of 8 rows x 128 B; wave w owns chunks w*6+i.
  const int lrow8 = lane >> 3;
  const int scol = 8 * ((lane & 7) ^ lrow8);      // pre-swizzled global col
  const u16* gsrc[6];
  const u16* lbase[6];
#pragma unroll
  for (int i = 0; i < 6; ++i) {
    const int chunk = w * 6 + i;
    if (chunk < 32) {   // A chunk
      const int row = chunk * 8 + lrow8;          // 0..255
      gsrc[i] = S + (size_t)(n0 + row) * N_NODES + scol;
      lbase[i] = &lds[chunk * 512];
    } else {            // B chunk
      const int row = (chunk - 32) * 8 + lrow8;   // 0..127
      gsrc[i] = Xt + (size_t)(j0 + row) * N_NODES + scol;
      lbase[i] = &lds[BOFF_U16 + (chunk - 32) * 512];
    }
  }

  const int wm = w >> 1, wn = w & 1;
  const int fr = lane & 15;
  const int khalf = lane >> 4;
  const int swz16 = (fr & 7) << 3;

  f32x4 acc[4][4];
#pragma unroll
  for (int i = 0; i < 4; ++i)
#pragma unroll
    for (int j = 0; j < 4; ++j) acc[i][j] = (f32x4)0.f;

#define STAGE3(tt, h)                                                     \
  {                                                                       \
    const int _s = (tt) % 3;                                              \
    _Pragma("unroll")                                                     \
    for (int i = (h) * 3; i < (h) * 3 + 3; ++i)                           \
      gload16(gsrc[i] + (size_t)(tt) * 64,                                \
              (void*)(lbase[i] + _s * SLOT_U16));                         \
  }

  // One phase: {8 ds_read, optional 3 gload, barrier, lgkm(0), 16 MFMA}.
#define PHASE(ksv, dostage, tt, h)                                        \
  {                                                                       \
    const u16* sa = &lds[s * SLOT_U16];                                   \
    const u16* sb = sa + BOFF_U16;                                        \
    const int c16 = ((ksv) * 32 + khalf * 8) ^ swz16;                     \
    bf16x8 a[4], b[4];                                                    \
    _Pragma("unroll")                                                     \
    for (int fm = 0; fm < 4; ++fm)                                        \
      a[fm] = *reinterpret_cast<const bf16x8*>(                           \
          &sa[(wm * 64 + fm * 16 + fr) * 64 + c16]);                      \
    _Pragma("unroll")                                                     \
    for (int fn = 0; fn < 4; ++fn)                                        \
      b[fn] = *reinterpret_cast<const bf16x8*>(                           \
          &sb[(wn * 64 + fn * 16 + fr) * 64 + c16]);                      \
    if (dostage) STAGE3(tt, h);                                           \
    __builtin_amdgcn_s_barrier();                                         \
    asm volatile("s_waitcnt lgkmcnt(0)" ::: "memory");                    \
    __builtin_amdgcn_sched_barrier(0);                                    \
    __builtin_amdgcn_s_setprio(1);                                        \
    _Pragma("unroll")                                                     \
    for (int fm = 0; fm < 4; ++fm)                                        \
      _Pragma("unroll")                                                   \
      for (int fn = 0; fn < 4; ++fn)                                      \
        acc[fm][fn] = __builtin_amdgcn_mfma_f32_16x16x32_bf16(            \
            a[fm], b[fn], acc[fm][fn], 0, 0, 0);                          \
    __builtin_amdgcn_s_setprio(0);                                        \
  }

  // prologue: tiles 0,1 -> slots 0,1
  STAGE3(0, 0); STAGE3(0, 1);
  STAGE3(1, 0); STAGE3(1, 1);

  int s = 0;
  for (int t = 0; t < 62; ++t) {
    asm volatile("s_waitcnt vmcnt(6)" ::: "memory");   // tile t landed
    __builtin_amdgcn_s_barrier();                      // B0 (data sync)
    PHASE(0, true, t + 2, 0);
    __builtin_amdgcn_s_barrier();                      // phase boundary
    PHASE(1, true, t + 2, 1);
    s = (s == 2) ? 0 : s + 1;
  }
  // t = 62 (tile 63 still in flight)
  asm volatile("s_waitcnt vmcnt(6)" ::: "memory");
  __builtin_amdgcn_s_barrier();
  PHASE(0, false, 0, 0);
  __builtin_amdgcn_s_barrier();
  PHASE(1, false, 0, 0);
  s = (s == 2) ? 0 : s + 1;
  // t = 63 (drain)
  asm volatile("s_waitcnt vmcnt(0)" ::: "memory");
  __builtin_amdgcn_s_barrier();
  PHASE(0, false, 0, 0);
  __builtin_amdgcn_s_barrier();
  PHASE(1, false, 0, 0);

  // epilogue: C/D layout col=lane&15, row=(lane>>4)*4+reg
  const int crow = (lane >> 4) * 4;
  const int ccol = lane & 15;
#pragma unroll
  for (int fm = 0; fm < 4; ++fm) {
    const int nrow = n0 + wm * 64 + fm * 16 + crow;
#pragma unroll
    for (int fn = 0; fn < 4; ++fn) {
      const int jcol = j0 + wn * 64 + fn * 16 + ccol;
#pragma unroll
      for (int r = 0; r < 4; ++r)
        Zb[(size_t)(nrow + r) * N_NODES + jcol] = f2bf(acc[fm][fn][r]);
    }
  }
#undef STAGE3
#undef PHASE
}

// ---------------------------------------------------------------------------
// Kernel C: per-node MFMA GEMM with in-block W-regen (R4 version — wp stays
// L2-hot; the wgen/Wall split measured slower in R5).
// ---------------------------------------------------------------------------
__global__ __launch_bounds__(256) void node_gemm_mfma(
    const float* __restrict__ x, const u16* __restrict__ Zb,
    const float* __restrict__ E, const float* __restrict__ wp,
    const float* __restrict__ bp, float* __restrict__ out) {
  __shared__ __align__(16) u16 Wt[2][64][LKP];
  __shared__ __align__(16) u16 Axz[2][64][LKP];
  __shared__ float biasS[2][64];
  __shared__ float EnS[2][EMB];
  const int n0 = blockIdx.x * 2;
  const int t = threadIdx.x;
  const int lane = t & 63;
  const int w = t >> 6;
  if (t < 2 * EMB) EnS[t / EMB][t % EMB] = E[n0 * EMB + t];
  __syncthreads();
  float en0[EMB], en1[EMB];
#pragma unroll
  for (int d = 0; d < EMB; ++d) { en0[d] = EnS[0][d]; en1[d] = EnS[1][d]; }

  if (t < 128) {
    const int nn = t >> 6, o = t & 63;
    float b = 0.f;
#pragma unroll
    for (int d = 0; d < EMB; ++d) b += EnS[nn][d] * bp[d * CO + o];
    biasS[nn][o] = b;
  }

  const float4* wp4 = reinterpret_cast<const float4*>(wp);
#pragma unroll
  for (int p = 0; p < 8; ++p) {
    const int e4 = p * 256 + t;
    const int ki = e4 >> 4, o4 = e4 & 15;
    float a0x = 0.f, a0y = 0.f, a0z = 0.f, a0w = 0.f;
    float a1x = 0.f, a1y = 0.f, a1z = 0.f, a1w = 0.f;
#pragma unroll
    for (int d = 0; d < EMB; ++d) {
      const float4 wv = wp4[d * 2048 + e4];
      a0x += en0[d] * wv.x; a0y += en0[d] * wv.y;
      a0z += en0[d] * wv.z; a0w += en0[d] * wv.w;
      a1x += en1[d] * wv.x; a1y += en1[d] * wv.y;
      a1z += en1[d] * wv.z; a1w += en1[d] * wv.w;
    }
    Wt[0][o4 * 4 + 0][ki] = f2bf(a0x); Wt[0][o4 * 4 + 1][ki] = f2bf(a0y);
    Wt[0][o4 * 4 + 2][ki] = f2bf(a0z); Wt[0][o4 * 4 + 3][ki] = f2bf(a0w);
    Wt[1][o4 * 4 + 0][ki] = f2bf(a1x); Wt[1][o4 * 4 + 1][ki] = f2bf(a1y);
    Wt[1][o4 * 4 + 2][ki] = f2bf(a1z); Wt[1][o4 * 4 + 3][ki] = f2bf(a1w);
  }

#pragma unroll
  for (int nn = 0; nn < 2; ++nn) {
    const int ng = n0 + nn;
#pragma unroll
    for (int pb = 0; pb < 4; ++pb) {
      const int b = pb * 16 + (t >> 4);
      const int i0 = (t & 15) * 4;
      const float4 xv = *reinterpret_cast<const float4*>(
          &x[(size_t)b * (N_NODES * CI) + (size_t)ng * CI + i0]);
      ushort4 uv;
      uv.x = f2bf(xv.x); uv.y = f2bf(xv.y); uv.z = f2bf(xv.z); uv.w = f2bf(xv.w);
      *reinterpret_cast<ushort4*>(&Axz[nn][b][i0]) = uv;
    }
#pragma unroll
    for (int pz = 0; pz < 4; ++pz) {
      const int t4 = pz * 256 + t;
      const int b = t4 >> 4, c0 = (t4 & 15) * 4;
      const ushort4 zv = *reinterpret_cast<const ushort4*>(
          &Zb[(size_t)ng * N_NODES + t4 * 4]);
      *reinterpret_cast<ushort4*>(&Axz[nn][b][64 + c0]) = zv;
    }
  }
  __syncthreads();

  const int nn = w >> 1, bh = w & 1;
  const int fr = lane & 15, fk = (lane >> 4) * 8;
  f32x4 acc[2][4];
#pragma unroll
  for (int m = 0; m < 2; ++m)
#pragma unroll
    for (int n = 0; n < 4; ++n) acc[m][n] = (f32x4)0.f;

#pragma unroll
  for (int kk = 0; kk < 4; ++kk) {
    bf16x8 a[2], b[4];
#pragma unroll
    for (int m = 0; m < 2; ++m)
      a[m] = *reinterpret_cast<const bf16x8*>(
          &Axz[nn][bh * 32 + m * 16 + fr][kk * 32 + fk]);
#pragma unroll
    for (int n = 0; n < 4; ++n)
      b[n] = *reinterpret_cast<const bf16x8*>(
          &Wt[nn][n * 16 + fr][kk * 32 + fk]);
#pragma unroll
    for (int m = 0; m < 2; ++m)
#pragma unroll
      for (int n = 0; n < 4; ++n)
        acc[m][n] = __builtin_amdgcn_mfma_f32_16x16x32_bf16(
            a[m], b[n], acc[m][n], 0, 0, 0);
  }

  const int crow = (lane >> 4) * 4;
  const int ccol = lane & 15;
  const int ng = n0 + nn;
#pragma unroll
  for (int m = 0; m < 2; ++m) {
#pragma unroll
    for (int n = 0; n < 4; ++n) {
      const int o = n * 16 + ccol;
      const float bv = biasS[nn][o];
#pragma unroll
      for (int r = 0; r < 4; ++r) {
        const int b = bh * 32 + m * 16 + crow + r;
        out[(size_t)b * (N_NODES * CI) + (size_t)ng * CI + o] =
            acc[m][n][r] + bv;
      }
    }
  }
}

// ---------------------------------------------------------------------------
extern "C" void kernel_launch(void* const* d_in, const int* in_sizes, int n_in,
                              void* d_out, int out_size, void* d_ws, size_t ws_size,
                              hipStream_t stream) {
  const float* x  = (const float*)d_in[0];   // [64, 4096, 64]
  const float* E  = (const float*)d_in[1];   // [4096, 10]
  const float* wp = (const float*)d_in[2];   // [10, 2, 64, 64]
  const float* bp = (const float*)d_in[3];   // [10, 64]
  float* out = (float*)d_out;                // [64, 4096, 64]
  const size_t MAT = (size_t)N_NODES * N_NODES;
  u16* Sb = (u16*)d_ws;                      // bf16 S    (33.5 MB)
  u16* Xt = Sb + MAT;                        // bf16 X^T  (33.5 MB)
  u16* Zb = Xt + MAT;                        // bf16 Z    (33.5 MB)

  front_fused<<<1024 + 4096, 256, 0, stream>>>(E, x, Sb, Xt);
  diffuse_gemm_pipe<<<512, 512, 0, stream>>>(Sb, Xt, Zb);
  node_gemm_mfma<<<N_NODES / 2, 256, 0, stream>>>(x, Zb, E, wp, bp, out);
}